// Round 4
// baseline (538.040 us; speedup 1.0000x reference)
//
#include <hip/hip_runtime.h>
#include <hip/hip_bf16.h>

#define BATCH 16
#define CIN   512
#define CMID  256
#define HWN   4096

typedef __bf16 bf16x8  __attribute__((ext_vector_type(8)));
typedef float  floatx4 __attribute__((ext_vector_type(4)));
typedef int    intx4   __attribute__((ext_vector_type(4)));

__device__ __forceinline__ unsigned short f2bf(float f){
  union { float f; unsigned int u; } v; v.f = f;
  unsigned int u = v.u;
  unsigned int r = u + 0x7FFFu + ((u >> 16) & 1u);   // RTNE
  return (unsigned short)(r >> 16);
}

__device__ __forceinline__ float wred(float v){
  #pragma unroll
  for (int o = 32; o >= 1; o >>= 1) v += __shfl_xor(v, o, 64);
  return v;
}

__device__ __forceinline__ float bsum(float v, float* scr, int t){
  v = wred(v);
  __syncthreads();
  if ((t & 63) == 0) scr[t >> 6] = v;
  __syncthreads();
  return scr[0] + scr[1] + scr[2] + scr[3];
}

__device__ __forceinline__ float bmax(float v, float* scr, int t){
  #pragma unroll
  for (int o = 32; o >= 1; o >>= 1) v = fmaxf(v, __shfl_xor(v, o, 64));
  __syncthreads();
  if ((t & 63) == 0) scr[t >> 6] = v;
  __syncthreads();
  return fmaxf(fmaxf(scr[0], scr[1]), fmaxf(scr[2], scr[3]));
}

// ---------------- K0: w_ql fp32 -> bf16 ----------------
__global__ __launch_bounds__(256) void k0_convert(const float* __restrict__ w,
                                                  unsigned short* __restrict__ wbf){
  int i = blockIdx.x * 256 + threadIdx.x;
  wbf[i] = f2bf(w[i]);
}

// ---------------- K1: bf16 MFMA GEMM g_x = w_ql * x, keep row-max; fused fp32 qr ----
__global__ __launch_bounds__(256) void k1_gemm(
    const float* __restrict__ x, const unsigned short* __restrict__ wbf,
    const float* __restrict__ w_qr, float* __restrict__ qr, float* __restrict__ gpart)
{
  __shared__ __align__(16) unsigned short Blds[2][64 * 32];  // 2 x 4 KB, swizzled 16B blocks
  __shared__ float wqr_s[CIN];

  const int t = threadIdx.x;
  const int ntile = blockIdx.x, b = blockIdx.y;
  const int n0 = ntile * 64;
  const int lane = t & 63, wave = t >> 6, quad = lane >> 4, lm = lane & 15;
  const int n_own = t >> 2, q_own = t & 3;
  const int wblk = (n_own * 4 + (q_own ^ (n_own & 3))) * 8;

  wqr_s[t] = w_qr[t];
  wqr_s[t + 256] = w_qr[t + 256];
  __syncthreads();   // wqr_s is read cross-wave below

  const float* xb = x + (size_t)b * CIN * HWN + (size_t)(q_own * 8) * HWN + n0 + n_own;

  floatx4 acc[4][4];
  #pragma unroll
  for (int i = 0; i < 4; ++i)
    #pragma unroll
    for (int jj = 0; jj < 4; ++jj)
      acc[i][jj] = (floatx4){0.f, 0.f, 0.f, 0.f};

  float qa = 0.f;
  float xv[8];
  bf16x8 afc[4], afn[4];

  #pragma unroll
  for (int j = 0; j < 8; ++j) xv[j] = xb[(size_t)j * HWN];
  #pragma unroll
  for (int j = 0; j < 8; ++j) qa = fmaf(wqr_s[q_own * 8 + j], xv[j], qa);
  {
    union { unsigned short u[8]; intx4 v; } pk;
    #pragma unroll
    for (int j = 0; j < 8; ++j) pk.u[j] = f2bf(xv[j]);
    *(intx4*)(&Blds[0][wblk]) = pk.v;
  }
  #pragma unroll
  for (int ms = 0; ms < 4; ++ms)
    afc[ms] = *(const bf16x8*)(&wbf[(size_t)(wave * 64 + ms * 16 + lm) * CIN + quad * 8]);
  __syncthreads();

  #pragma unroll 2
  for (int kt = 0; kt < 16; ++kt){
    const int cur = kt & 1;
    if (kt < 15){
      #pragma unroll
      for (int j = 0; j < 8; ++j) xv[j] = xb[(size_t)((kt + 1) * 32 + j) * HWN];
      #pragma unroll
      for (int ms = 0; ms < 4; ++ms)
        afn[ms] = *(const bf16x8*)(&wbf[(size_t)(wave * 64 + ms * 16 + lm) * CIN +
                                        (kt + 1) * 32 + quad * 8]);
    }
    bf16x8 bfr[4];
    #pragma unroll
    for (int ns = 0; ns < 4; ++ns){
      const int n = ns * 16 + lm;
      bfr[ns] = *(const bf16x8*)(&Blds[cur][(n * 4 + (quad ^ (n & 3))) * 8]);
    }
    #pragma unroll
    for (int ms = 0; ms < 4; ++ms)
      #pragma unroll
      for (int ns = 0; ns < 4; ++ns)
        acc[ms][ns] = __builtin_amdgcn_mfma_f32_16x16x32_bf16(afc[ms], bfr[ns], acc[ms][ns], 0, 0, 0);
    if (kt < 15){
      #pragma unroll
      for (int j = 0; j < 8; ++j)
        qa = fmaf(wqr_s[(kt + 1) * 32 + q_own * 8 + j], xv[j], qa);
      union { unsigned short u[8]; intx4 v; } pk;
      #pragma unroll
      for (int j = 0; j < 8; ++j) pk.u[j] = f2bf(xv[j]);
      *(intx4*)(&Blds[1 - cur][wblk]) = pk.v;
      #pragma unroll
      for (int ms = 0; ms < 4; ++ms) afc[ms] = afn[ms];
    }
    __syncthreads();
  }

  qa += __shfl_xor(qa, 1, 64);
  qa += __shfl_xor(qa, 2, 64);
  if ((t & 3) == 0) qr[b * HWN + n0 + n_own] = qa;

  #pragma unroll
  for (int ms = 0; ms < 4; ++ms){
    #pragma unroll
    for (int r = 0; r < 4; ++r){
      float v = fmaxf(fmaxf(acc[ms][0][r], acc[ms][1][r]),
                      fmaxf(acc[ms][2][r], acc[ms][3][r]));
      v = fmaxf(v, __shfl_xor(v, 1, 64));
      v = fmaxf(v, __shfl_xor(v, 2, 64));
      v = fmaxf(v, __shfl_xor(v, 4, 64));
      v = fmaxf(v, __shfl_xor(v, 8, 64));
      if ((lane & 15) == 0){
        const int m = wave * 64 + ms * 16 + (lane >> 4) * 4 + r;
        gpart[((b * 64 + ntile) * CMID) + m] = v;
      }
    }
  }
}

// ---------------- K2: per-b softmaxes + wmix; also zeroes the K3 atomic buffers ----
__global__ __launch_bounds__(256) void k2_small(
    const float* __restrict__ gpart, const float* __restrict__ b_ql,
    const float* __restrict__ w_vl, const float* __restrict__ qr,
    float* __restrict__ wmix, float* __restrict__ stats,
    float* __restrict__ xmask, float* __restrict__ ctx)
{
  __shared__ float scr[4];
  __shared__ float avg_s[CMID];
  const int b = blockIdx.x, t = threadIdx.x;

  // zero atomic accumulators for K3 (replaces hipMemsetAsync dispatch)
  xmask[b*CIN + t] = 0.f;
  xmask[b*CIN + t + 256] = 0.f;
  {
    floatx4 z = (floatx4){0.f,0.f,0.f,0.f};
    floatx4* cz = (floatx4*)(ctx + b*HWN);
    #pragma unroll
    for (int r = 0; r < 4; ++r) cz[t + r*256] = z;
  }

  float gm = -3.0e38f;
  for (int nt = 0; nt < 64; ++nt)
    gm = fmaxf(gm, gpart[(b*64 + nt) * CMID + t]);
  gm += b_ql[t];

  float mx = bmax(gm, scr, t);
  float e = expf(gm - mx);
  float s = bsum(e, scr, t);
  avg_s[t] = e / s;
  __syncthreads();

  float w0 = 0.f, w1 = 0.f;
  for (int m = 0; m < CMID; ++m){
    float a = avg_s[m];
    w0 = fmaf(a, w_vl[m*CIN + t], w0);
    w1 = fmaf(a, w_vl[m*CIN + t + 256], w1);
  }
  wmix[b*CIN + t] = w0;
  wmix[b*CIN + t + 256] = w1;

  const float* qb = qr + b*HWN;
  float qm = -3.0e38f;
  for (int i = t; i < HWN; i += 256) qm = fmaxf(qm, qb[i]);
  qm = bmax(qm, scr, t);
  float qs = 0.f;
  for (int i = t; i < HWN; i += 256) qs += expf(qb[i] - qm);
  qs = bsum(qs, scr, t);
  if (t == 0){ stats[b] = qm; stats[16 + b] = qs; }
}

// ---------------- K3: one pass over x: xmask[b,c]=sum_h x*mask ; ctx[b,h]=sum_c wmix*x ----
__global__ __launch_bounds__(256) void k3_dual(
    const float* __restrict__ x, const float* __restrict__ qr,
    const float* __restrict__ stats, const float* __restrict__ wmix,
    float* __restrict__ xmask, float* __restrict__ ctx)
{
  const int ht = blockIdx.x, ct = blockIdx.y, b = blockIdx.z;
  const int t = threadIdx.x;
  const int j = t & 15, i = t >> 4;
  const int c0 = ct * 128, h0 = ht * 128;
  const float* xb = x + (size_t)b * CIN * HWN;
  const float qm = stats[b], inv_qs = 1.0f / stats[16 + b];

  floatx4 maskv[2];
  #pragma unroll
  for (int l = 0; l < 2; ++l)
    #pragma unroll
    for (int d = 0; d < 4; ++d)
      maskv[l][d] = expf(qr[b*HWN + h0 + j*4 + d + 64*l] - qm) * inv_qs;

  float wmv[8];
  #pragma unroll
  for (int k = 0; k < 8; ++k)
    wmv[k] = wmix[b*CIN + c0 + i + 16*k];

  float xm[8] = {0,0,0,0,0,0,0,0};
  floatx4 cx[2];
  cx[0] = (floatx4){0.f,0.f,0.f,0.f};
  cx[1] = (floatx4){0.f,0.f,0.f,0.f};

  #pragma unroll
  for (int k = 0; k < 8; ++k){
    const float* row = xb + (size_t)(c0 + i + 16*k) * HWN + h0 + j*4;
    floatx4 v0 = *(const floatx4*)(row);
    floatx4 v1 = *(const floatx4*)(row + 64);
    floatx4 p = v0 * maskv[0] + v1 * maskv[1];
    xm[k] = (p[0] + p[1]) + (p[2] + p[3]);
    cx[0] += v0 * wmv[k];
    cx[1] += v1 * wmv[k];
  }

  #pragma unroll
  for (int k = 0; k < 8; ++k){
    float v = xm[k];
    v += __shfl_xor(v, 1, 64); v += __shfl_xor(v, 2, 64);
    v += __shfl_xor(v, 4, 64); v += __shfl_xor(v, 8, 64);
    if (j == 0) atomicAdd(&xmask[b*CIN + c0 + i + 16*k], v);
  }
  #pragma unroll
  for (int l = 0; l < 2; ++l)
    #pragma unroll
    for (int d = 0; d < 4; ++d){
      float v = cx[l][d];
      v += __shfl_xor(v, 16, 64); v += __shfl_xor(v, 32, 64);
      if (((t & 63) >> 4) == 0) atomicAdd(&ctx[b*HWN + h0 + j*4 + d + 64*l], v);
    }
}

// ---------------- K4: per-b channel tail + sk-attn + spatial softmax -> P, Q, sp ----
// GEMVs are wave-per-row with coalesced float4 row reads + butterfly reduce
// (round-3's per-thread-row reads were 64-cache-lines-per-load uncoalesced).
__global__ __launch_bounds__(256) void k4_tail(
    const float* __restrict__ xmask, const float* __restrict__ w_vr, const float* __restrict__ b_vr,
    const float* __restrict__ w_up, const float* __restrict__ b_up,
    const float* __restrict__ ln_g, const float* __restrict__ ln_b,
    const float* __restrict__ w_red, const float* __restrict__ bn_g, const float* __restrict__ bn_b,
    const float* __restrict__ bn_rm, const float* __restrict__ bn_rv,
    const float* __restrict__ w_sel, const float* __restrict__ ctxg,
    float* __restrict__ P, float* __restrict__ Q, float* __restrict__ sp)
{
  __shared__ float scr[4];
  __shared__ float xm_s[CIN];
  __shared__ float cm_s[CMID];
  __shared__ float up_s[CIN];
  __shared__ float ch_s[CIN];
  __shared__ float red_s[32];
  const int b = blockIdx.x, t = threadIdx.x;
  const int lane = t & 63, wave = t >> 6;

  xm_s[t] = xmask[b*CIN + t];
  xm_s[t + 256] = xmask[b*CIN + t + 256];
  __syncthreads();

  // context[m] = w_vr[m,:]. xm + b_vr[m] ; wave-per-row (row = 2 KB, coalesced)
  {
    floatx4 xa = *(const floatx4*)(&xm_s[lane * 8]);
    floatx4 xb2 = *(const floatx4*)(&xm_s[lane * 8 + 4]);
    for (int mi = 0; mi < 64; ++mi){
      const int m = wave * 64 + mi;
      const float* wr = w_vr + (size_t)m * CIN + lane * 8;
      floatx4 a = *(const floatx4*)(wr);
      floatx4 c = *(const floatx4*)(wr + 4);
      floatx4 pr = a * xa + c * xb2;
      float acc = wred((pr[0] + pr[1]) + (pr[2] + pr[3]));
      if (lane == 0) cm_s[m] = acc + b_vr[m];
    }
  }
  __syncthreads();

  // up[o] = w_up[o,:] . cm + b_up[o] ; wave-per-row (row = 1 KB, coalesced)
  {
    floatx4 ca = *(const floatx4*)(&cm_s[lane * 4]);
    for (int oi = 0; oi < 128; ++oi){
      const int o = wave * 128 + oi;
      floatx4 a = *(const floatx4*)(w_up + (size_t)o * CMID + lane * 4);
      floatx4 pr = a * ca;
      float acc = wred((pr[0] + pr[1]) + (pr[2] + pr[3]));
      if (lane == 0) up_s[o] = acc + b_up[o];
    }
  }
  __syncthreads();

  // LayerNorm over 512 + sigmoid
  float up0 = up_s[t], up1 = up_s[t + 256];
  float mu = bsum(up0 + up1, scr, t) * (1.0f / 512.0f);
  float d0 = up0 - mu, d1 = up1 - mu;
  float var = bsum(d0*d0 + d1*d1, scr, t) * (1.0f / 512.0f);
  float rstd = rsqrtf(var + 1e-5f);
  float ch0 = 1.f / (1.f + expf(-(d0 * rstd * ln_g[t] + ln_b[t])));
  float ch1 = 1.f / (1.f + expf(-(d1 * rstd * ln_g[t + 256] + ln_b[t + 256])));
  ch_s[t] = ch0; ch_s[t + 256] = ch1;
  __syncthreads();

  // red[a] from closed-form s[c] = ch*(1+1/HW) + 1/HW ; wave-per-row (32 rows)
  {
    const float k1 = 1.0f + 1.0f/4096.0f, k2 = 1.0f/4096.0f;
    floatx4 sa, sb;
    #pragma unroll
    for (int d = 0; d < 4; ++d){
      sa[d] = fmaf(ch_s[lane*8 + d], k1, k2);
      sb[d] = fmaf(ch_s[lane*8 + 4 + d], k1, k2);
    }
    for (int ai = 0; ai < 8; ++ai){
      const int a = wave * 8 + ai;
      const float* wr = w_red + (size_t)a * CIN + lane * 8;
      floatx4 u = *(const floatx4*)(wr);
      floatx4 v = *(const floatx4*)(wr + 4);
      floatx4 pr = u * sa + v * sb;
      float acc = wred((pr[0] + pr[1]) + (pr[2] + pr[3]));
      if (lane == 0){
        float bn = (acc - bn_rm[a]) * rsqrtf(bn_rv[a] + 1e-5f) * bn_g[a] + bn_b[a];
        red_s[a] = fmaxf(bn, 0.0f);
      }
    }
  }
  __syncthreads();

  #pragma unroll
  for (int q = 0; q < 2; ++q){
    const int c = t + q * 256;
    float s0 = 0.f, s1 = 0.f;
    const float* ws0 = w_sel + (size_t)c * 32;
    const float* ws1 = w_sel + (size_t)(CIN + c) * 32;
    #pragma unroll
    for (int a = 0; a < 32; ++a){
      s0 = fmaf(ws0[a], red_s[a], s0);
      s1 = fmaf(ws1[a], red_s[a], s1);
    }
    float a0 = 1.f / (1.f + expf(s1 - s0));
    float a1 = 1.f - a0;
    float ch = ch_s[c];
    P[b*CIN + c] = 1.0f + a1 * ch;
    Q[b*CIN + c] = a0 * ch + a1;
  }

  const float* cb = ctxg + b * HWN;
  float cm = -3.0e38f;
  for (int h = t; h < HWN; h += 256) cm = fmaxf(cm, cb[h]);
  cm = bmax(cm, scr, t);
  float cs = 0.f;
  for (int h = t; h < HWN; h += 256) cs += expf(cb[h] - cm);
  cs = bsum(cs, scr, t);
  const float inv = 1.0f / cs;
  for (int h = t; h < HWN; h += 256) sp[b*HWN + h] = expf(cb[h] - cm) * inv;
}

// ---------------- K5: out = x * (P + sp * Q), one block per (b,c) row ----------------
__global__ __launch_bounds__(256) void k5_out(
    const float* __restrict__ x, const float* __restrict__ P, const float* __restrict__ Q,
    const float* __restrict__ sp, float* __restrict__ out)
{
  const int bc = blockIdx.x;
  const int b = bc >> 9;
  const int t = threadIdx.x;
  const float p = P[bc], q = Q[bc];
  const floatx4* xr = (const floatx4*)(x + (size_t)bc * HWN);
  const floatx4* sr = (const floatx4*)(sp + (size_t)b * HWN);
  floatx4* outr = (floatx4*)(out + (size_t)bc * HWN);
  #pragma unroll
  for (int r = 0; r < 4; ++r){
    const int idx = t + r * 256;
    floatx4 xv = xr[idx];
    floatx4 sv = sr[idx];
    outr[idx] = xv * (p + sv * q);
  }
}

extern "C" void kernel_launch(void* const* d_in, const int* in_sizes, int n_in,
                              void* d_out, int out_size, void* d_ws, size_t ws_size,
                              hipStream_t stream)
{
  (void)in_sizes; (void)n_in; (void)out_size; (void)ws_size;
  const float* x    = (const float*)d_in[0];
  const float* w_qr = (const float*)d_in[1];
  const float* w_vr = (const float*)d_in[3];
  const float* b_vr = (const float*)d_in[4];
  const float* w_up = (const float*)d_in[5];
  const float* b_up = (const float*)d_in[6];
  const float* ln_g = (const float*)d_in[7];
  const float* ln_b = (const float*)d_in[8];
  const float* w_ql = (const float*)d_in[9];
  const float* b_ql = (const float*)d_in[10];
  const float* w_vl = (const float*)d_in[11];
  const float* w_red = (const float*)d_in[13];
  const float* bn_g  = (const float*)d_in[14];
  const float* bn_b  = (const float*)d_in[15];
  const float* bn_rm = (const float*)d_in[16];
  const float* bn_rv = (const float*)d_in[17];
  const float* w_sel = (const float*)d_in[18];
  float* out = (float*)d_out;

  char* ws = (char*)d_ws;
  unsigned short* wbf = (unsigned short*)(ws + 0);   //  262144 B
  float* qr    = (float*)(ws + 262144);              //  262144 B
  float* gpart = (float*)(ws + 524288);              // 1048576 B
  float* wmix  = (float*)(ws + 1572864);             //   32768 B
  float* xmask = (float*)(ws + 1605632);             //   32768 B (atomic, zeroed in K2)
  float* ctx   = (float*)(ws + 1638400);             //  262144 B (atomic, zeroed in K2)
  float* sp    = (float*)(ws + 1900544);             //  262144 B
  float* P     = (float*)(ws + 2162688);             //   32768 B
  float* Q     = (float*)(ws + 2195456);             //   32768 B
  float* stats = (float*)(ws + 2228224);             //     128 B

  k0_convert<<<512, 256, 0, stream>>>(w_ql, wbf);
  k1_gemm<<<dim3(64, BATCH), 256, 0, stream>>>(x, wbf, w_qr, qr, gpart);
  k2_small<<<BATCH, 256, 0, stream>>>(gpart, b_ql, w_vl, qr, wmix, stats, xmask, ctx);
  k3_dual<<<dim3(32, 4, BATCH), 256, 0, stream>>>(x, qr, stats, wmix, xmask, ctx);
  k4_tail<<<BATCH, 256, 0, stream>>>(xmask, w_vr, b_vr, w_up, b_up, ln_g, ln_b,
                                     w_red, bn_g, bn_b, bn_rm, bn_rv, w_sel, ctx,
                                     P, Q, sp);
  k5_out<<<BATCH * CIN, 256, 0, stream>>>(x, P, Q, sp, out);
}

// Round 5
// 395.392 us; speedup vs baseline: 1.3608x; 1.3608x over previous
//
#include <hip/hip_runtime.h>
#include <hip/hip_bf16.h>

#define BATCH 16
#define CIN   512
#define CMID  256
#define HWN   4096

typedef __bf16 bf16x8  __attribute__((ext_vector_type(8)));
typedef float  floatx4 __attribute__((ext_vector_type(4)));
typedef int    intx4   __attribute__((ext_vector_type(4)));

__device__ __forceinline__ unsigned short f2bf(float f){
  union { float f; unsigned int u; } v; v.f = f;
  unsigned int u = v.u;
  unsigned int r = u + 0x7FFFu + ((u >> 16) & 1u);   // RTNE
  return (unsigned short)(r >> 16);
}

__device__ __forceinline__ float wred(float v){
  #pragma unroll
  for (int o = 32; o >= 1; o >>= 1) v += __shfl_xor(v, o, 64);
  return v;
}

__device__ __forceinline__ float bsum(float v, float* scr, int t){
  v = wred(v);
  __syncthreads();
  if ((t & 63) == 0) scr[t >> 6] = v;
  __syncthreads();
  return scr[0] + scr[1] + scr[2] + scr[3];
}

__device__ __forceinline__ float bmax(float v, float* scr, int t){
  #pragma unroll
  for (int o = 32; o >= 1; o >>= 1) v = fmaxf(v, __shfl_xor(v, o, 64));
  __syncthreads();
  if ((t & 63) == 0) scr[t >> 6] = v;
  __syncthreads();
  return fmaxf(fmaxf(scr[0], scr[1]), fmaxf(scr[2], scr[3]));
}

// ---------------- K0: w_ql fp32 -> bf16 ----------------
__global__ __launch_bounds__(256) void k0_convert(const float* __restrict__ w,
                                                  unsigned short* __restrict__ wbf){
  int i = blockIdx.x * 256 + threadIdx.x;
  wbf[i] = f2bf(w[i]);
}

// ---------------- K1: bf16 MFMA GEMM g_x = w_ql * x, keep row-max; fused fp32 qr ----
__global__ __launch_bounds__(256) void k1_gemm(
    const float* __restrict__ x, const unsigned short* __restrict__ wbf,
    const float* __restrict__ w_qr, float* __restrict__ qr, float* __restrict__ gpart)
{
  __shared__ __align__(16) unsigned short Blds[2][64 * 32];
  __shared__ float wqr_s[CIN];

  const int t = threadIdx.x;
  const int ntile = blockIdx.x, b = blockIdx.y;
  const int n0 = ntile * 64;
  const int lane = t & 63, wave = t >> 6, quad = lane >> 4, lm = lane & 15;
  const int n_own = t >> 2, q_own = t & 3;
  const int wblk = (n_own * 4 + (q_own ^ (n_own & 3))) * 8;

  wqr_s[t] = w_qr[t];
  wqr_s[t + 256] = w_qr[t + 256];
  __syncthreads();

  const float* xb = x + (size_t)b * CIN * HWN + (size_t)(q_own * 8) * HWN + n0 + n_own;

  floatx4 acc[4][4];
  #pragma unroll
  for (int i = 0; i < 4; ++i)
    #pragma unroll
    for (int jj = 0; jj < 4; ++jj)
      acc[i][jj] = (floatx4){0.f, 0.f, 0.f, 0.f};

  float qa = 0.f;
  float xv[8];
  bf16x8 afc[4], afn[4];

  #pragma unroll
  for (int j = 0; j < 8; ++j) xv[j] = xb[(size_t)j * HWN];
  #pragma unroll
  for (int j = 0; j < 8; ++j) qa = fmaf(wqr_s[q_own * 8 + j], xv[j], qa);
  {
    union { unsigned short u[8]; intx4 v; } pk;
    #pragma unroll
    for (int j = 0; j < 8; ++j) pk.u[j] = f2bf(xv[j]);
    *(intx4*)(&Blds[0][wblk]) = pk.v;
  }
  #pragma unroll
  for (int ms = 0; ms < 4; ++ms)
    afc[ms] = *(const bf16x8*)(&wbf[(size_t)(wave * 64 + ms * 16 + lm) * CIN + quad * 8]);
  __syncthreads();

  #pragma unroll 2
  for (int kt = 0; kt < 16; ++kt){
    const int cur = kt & 1;
    if (kt < 15){
      #pragma unroll
      for (int j = 0; j < 8; ++j) xv[j] = xb[(size_t)((kt + 1) * 32 + j) * HWN];
      #pragma unroll
      for (int ms = 0; ms < 4; ++ms)
        afn[ms] = *(const bf16x8*)(&wbf[(size_t)(wave * 64 + ms * 16 + lm) * CIN +
                                        (kt + 1) * 32 + quad * 8]);
    }
    bf16x8 bfr[4];
    #pragma unroll
    for (int ns = 0; ns < 4; ++ns){
      const int n = ns * 16 + lm;
      bfr[ns] = *(const bf16x8*)(&Blds[cur][(n * 4 + (quad ^ (n & 3))) * 8]);
    }
    #pragma unroll
    for (int ms = 0; ms < 4; ++ms)
      #pragma unroll
      for (int ns = 0; ns < 4; ++ns)
        acc[ms][ns] = __builtin_amdgcn_mfma_f32_16x16x32_bf16(afc[ms], bfr[ns], acc[ms][ns], 0, 0, 0);
    if (kt < 15){
      #pragma unroll
      for (int j = 0; j < 8; ++j)
        qa = fmaf(wqr_s[(kt + 1) * 32 + q_own * 8 + j], xv[j], qa);
      union { unsigned short u[8]; intx4 v; } pk;
      #pragma unroll
      for (int j = 0; j < 8; ++j) pk.u[j] = f2bf(xv[j]);
      *(intx4*)(&Blds[1 - cur][wblk]) = pk.v;
      #pragma unroll
      for (int ms = 0; ms < 4; ++ms) afc[ms] = afn[ms];
    }
    __syncthreads();
  }

  qa += __shfl_xor(qa, 1, 64);
  qa += __shfl_xor(qa, 2, 64);
  if ((t & 3) == 0) qr[b * HWN + n0 + n_own] = qa;

  #pragma unroll
  for (int ms = 0; ms < 4; ++ms){
    #pragma unroll
    for (int r = 0; r < 4; ++r){
      float v = fmaxf(fmaxf(acc[ms][0][r], acc[ms][1][r]),
                      fmaxf(acc[ms][2][r], acc[ms][3][r]));
      v = fmaxf(v, __shfl_xor(v, 1, 64));
      v = fmaxf(v, __shfl_xor(v, 2, 64));
      v = fmaxf(v, __shfl_xor(v, 4, 64));
      v = fmaxf(v, __shfl_xor(v, 8, 64));
      if ((lane & 15) == 0){
        const int m = wave * 64 + ms * 16 + (lane >> 4) * 4 + r;
        gpart[((b * 64 + ntile) * CMID) + m] = v;
      }
    }
  }
}

// ---------------- KR1: gmax[b,m] = max_nt gpart[b,nt,m] + b_ql[m] ; grid (16,8) ----
__global__ __launch_bounds__(256) void kr1_gmax(
    const float* __restrict__ gpart, const float* __restrict__ b_ql,
    float* __restrict__ gmax)
{
  __shared__ float part[8][32];
  const int b = blockIdx.x, g = blockIdx.y, t = threadIdx.x;
  const int m_l = t & 31, ng = t >> 5;
  const int m = g * 32 + m_l;
  float v = -3.0e38f;
  #pragma unroll
  for (int i = 0; i < 8; ++i)
    v = fmaxf(v, gpart[(size_t)(b * 64 + ng * 8 + i) * CMID + m]);
  part[ng][m_l] = v;
  __syncthreads();
  if (t < 32){
    float mx = part[0][t];
    #pragma unroll
    for (int i = 1; i < 8; ++i) mx = fmaxf(mx, part[i][t]);
    gmax[b * CMID + g * 32 + t] = mx + b_ql[g * 32 + t];
  }
}

// ---------------- KR2: grid (16,5). cg<4: softmax(gmax)->wmix slice + zero ctx quarter.
//                  cg==4: qr softmax stats + zero xmask. ----
__global__ __launch_bounds__(256) void kr2_prep(
    const float* __restrict__ gmax, const float* __restrict__ w_vl,
    const float* __restrict__ qr,
    float* __restrict__ wmix, float* __restrict__ stats,
    float* __restrict__ xmask, float* __restrict__ ctx)
{
  __shared__ float scr[4];
  __shared__ float avg_s[CMID];
  __shared__ float wsum[2][128];
  const int b = blockIdx.x, cg = blockIdx.y, t = threadIdx.x;

  if (cg < 4){
    // zero this ctx quarter (1024 floats)
    ((floatx4*)(ctx + (size_t)b * HWN + cg * 1024))[t] = (floatx4){0.f,0.f,0.f,0.f};

    float gv = gmax[b * CMID + t];
    float mx = bmax(gv, scr, t);
    float e = expf(gv - mx);
    float s = bsum(e, scr, t);
    avg_s[t] = e / s;
    __syncthreads();

    const int c = cg * 128 + (t & 127);
    const int half = t >> 7;
    float acc = 0.f;
    #pragma unroll 8
    for (int mi = 0; mi < 128; ++mi){
      const int m = half * 128 + mi;
      acc = fmaf(w_vl[(size_t)m * CIN + c], avg_s[m], acc);
    }
    wsum[half][t & 127] = acc;
    __syncthreads();
    if (t < 128) wmix[b * CIN + cg * 128 + t] = wsum[0][t] + wsum[1][t];
  } else {
    xmask[b * CIN + t] = 0.f;
    xmask[b * CIN + t + 256] = 0.f;
    const float* qb = qr + (size_t)b * HWN;
    float qm = -3.0e38f;
    #pragma unroll
    for (int i = 0; i < 16; ++i) qm = fmaxf(qm, qb[t + i * 256]);
    qm = bmax(qm, scr, t);
    float qs = 0.f;
    #pragma unroll
    for (int i = 0; i < 16; ++i) qs += expf(qb[t + i * 256] - qm);
    qs = bsum(qs, scr, t);
    if (t == 0){ stats[b] = qm; stats[16 + b] = qs; }
  }
}

// ---------------- K3: one pass over x: xmask[b,c]=sum_h x*mask ; ctx[b,h]=sum_c wmix*x ----
__global__ __launch_bounds__(256) void k3_dual(
    const float* __restrict__ x, const float* __restrict__ qr,
    const float* __restrict__ stats, const float* __restrict__ wmix,
    float* __restrict__ xmask, float* __restrict__ ctx)
{
  const int ht = blockIdx.x, ct = blockIdx.y, b = blockIdx.z;
  const int t = threadIdx.x;
  const int j = t & 15, i = t >> 4;
  const int c0 = ct * 128, h0 = ht * 128;
  const float* xb = x + (size_t)b * CIN * HWN;
  const float qm = stats[b], inv_qs = 1.0f / stats[16 + b];

  floatx4 maskv[2];
  #pragma unroll
  for (int l = 0; l < 2; ++l)
    #pragma unroll
    for (int d = 0; d < 4; ++d)
      maskv[l][d] = expf(qr[b*HWN + h0 + j*4 + d + 64*l] - qm) * inv_qs;

  float wmv[8];
  #pragma unroll
  for (int k = 0; k < 8; ++k)
    wmv[k] = wmix[b*CIN + c0 + i + 16*k];

  float xm[8] = {0,0,0,0,0,0,0,0};
  floatx4 cx[2];
  cx[0] = (floatx4){0.f,0.f,0.f,0.f};
  cx[1] = (floatx4){0.f,0.f,0.f,0.f};

  #pragma unroll
  for (int k = 0; k < 8; ++k){
    const float* row = xb + (size_t)(c0 + i + 16*k) * HWN + h0 + j*4;
    floatx4 v0 = *(const floatx4*)(row);
    floatx4 v1 = *(const floatx4*)(row + 64);
    floatx4 p = v0 * maskv[0] + v1 * maskv[1];
    xm[k] = (p[0] + p[1]) + (p[2] + p[3]);
    cx[0] += v0 * wmv[k];
    cx[1] += v1 * wmv[k];
  }

  #pragma unroll
  for (int k = 0; k < 8; ++k){
    float v = xm[k];
    v += __shfl_xor(v, 1, 64); v += __shfl_xor(v, 2, 64);
    v += __shfl_xor(v, 4, 64); v += __shfl_xor(v, 8, 64);
    if (j == 0) atomicAdd(&xmask[b*CIN + c0 + i + 16*k], v);
  }
  #pragma unroll
  for (int l = 0; l < 2; ++l)
    #pragma unroll
    for (int d = 0; d < 4; ++d){
      float v = cx[l][d];
      v += __shfl_xor(v, 16, 64); v += __shfl_xor(v, 32, 64);
      if (((t & 63) >> 4) == 0) atomicAdd(&ctx[b*HWN + h0 + j*4 + d + 64*l], v);
    }
}

// ---------------- KR4: context[b,m] = w_vr[m,:].xmask[b] + b_vr[m] ; grid (16,2) ----
// 16 lanes per row, lanes read CONSECUTIVE float4s (256B coalesced per instr).
__global__ __launch_bounds__(256) void kr4_context(
    const float* __restrict__ xmask, const float* __restrict__ w_vr,
    const float* __restrict__ b_vr, float* __restrict__ ctxm)
{
  __shared__ __align__(16) float xm_s[CIN];
  const int b = blockIdx.x, half = blockIdx.y, t = threadIdx.x;
  const int kl = t & 15, rg = t >> 4;

  xm_s[t] = xmask[b * CIN + t];
  xm_s[t + 256] = xmask[b * CIN + t + 256];
  __syncthreads();

  floatx4 xf[8];
  #pragma unroll
  for (int jf = 0; jf < 8; ++jf)
    xf[jf] = *(const floatx4*)(&xm_s[(jf * 16 + kl) * 4]);

  #pragma unroll
  for (int pass = 0; pass < 8; ++pass){
    const int m = half * 128 + pass * 16 + rg;
    const floatx4* wr = (const floatx4*)(w_vr + (size_t)m * CIN);
    floatx4 pacc = (floatx4){0.f,0.f,0.f,0.f};
    #pragma unroll
    for (int jf = 0; jf < 8; ++jf)
      pacc += wr[jf * 16 + kl] * xf[jf];
    float acc = (pacc[0] + pacc[1]) + (pacc[2] + pacc[3]);
    acc += __shfl_xor(acc, 1, 64); acc += __shfl_xor(acc, 2, 64);
    acc += __shfl_xor(acc, 4, 64); acc += __shfl_xor(acc, 8, 64);
    if (kl == 0) ctxm[b * CMID + m] = acc + b_vr[m];
  }
}

// ---------------- KR5: up + LN + ch + red + sel -> P,Q ; spatial softmax -> sp ; grid 16 ----
__global__ __launch_bounds__(256) void kr5_tail(
    const float* __restrict__ ctxm, const float* __restrict__ w_up, const float* __restrict__ b_up,
    const float* __restrict__ ln_g, const float* __restrict__ ln_b,
    const float* __restrict__ w_red, const float* __restrict__ bn_g, const float* __restrict__ bn_b,
    const float* __restrict__ bn_rm, const float* __restrict__ bn_rv,
    const float* __restrict__ w_sel, const float* __restrict__ ctxg,
    float* __restrict__ P, float* __restrict__ Q, float* __restrict__ sp)
{
  __shared__ float scr[4];
  __shared__ __align__(16) float cm_s[CMID];
  __shared__ __align__(16) float up_s[CIN];
  __shared__ __align__(16) float ch_s[CIN];
  __shared__ float red_s[32];
  const int b = blockIdx.x, t = threadIdx.x;

  cm_s[t] = ctxm[b * CMID + t];
  __syncthreads();

  // up[o] = w_up[o,:].cm ; 8 lanes/row, coalesced 128B per instr
  {
    const int kl = t & 7;
    floatx4 cf[8];
    #pragma unroll
    for (int jf = 0; jf < 8; ++jf)
      cf[jf] = *(const floatx4*)(&cm_s[(jf * 8 + kl) * 4]);
    #pragma unroll
    for (int pass = 0; pass < 16; ++pass){
      const int o = pass * 32 + (t >> 3);
      const floatx4* wr = (const floatx4*)(w_up + (size_t)o * CMID);
      floatx4 pacc = (floatx4){0.f,0.f,0.f,0.f};
      #pragma unroll
      for (int jf = 0; jf < 8; ++jf)
        pacc += wr[jf * 8 + kl] * cf[jf];
      float acc = (pacc[0] + pacc[1]) + (pacc[2] + pacc[3]);
      acc += __shfl_xor(acc, 1, 64); acc += __shfl_xor(acc, 2, 64);
      acc += __shfl_xor(acc, 4, 64);
      if (kl == 0) up_s[o] = acc + b_up[o];
    }
  }
  __syncthreads();

  // LayerNorm over 512 + sigmoid
  float up0 = up_s[t], up1 = up_s[t + 256];
  float mu = bsum(up0 + up1, scr, t) * (1.0f / 512.0f);
  float d0 = up0 - mu, d1 = up1 - mu;
  float var = bsum(d0*d0 + d1*d1, scr, t) * (1.0f / 512.0f);
  float rstd = rsqrtf(var + 1e-5f);
  float ch0 = 1.f / (1.f + expf(-(d0 * rstd * ln_g[t] + ln_b[t])));
  float ch1 = 1.f / (1.f + expf(-(d1 * rstd * ln_g[t + 256] + ln_b[t + 256])));
  ch_s[t] = ch0; ch_s[t + 256] = ch1;
  __syncthreads();

  // red[a] ; 8 lanes/row over K=512, single pass (a = t>>3)
  {
    const int kl = t & 7, a = t >> 3;
    const float k1 = 1.0f + 1.0f/4096.0f, k2 = 1.0f/4096.0f;
    const floatx4* wrd = (const floatx4*)(w_red + (size_t)a * CIN);
    float racc = 0.f;
    #pragma unroll
    for (int jf = 0; jf < 16; ++jf){
      floatx4 wv = wrd[jf * 8 + kl];
      floatx4 cv = *(const floatx4*)(&ch_s[(jf * 8 + kl) * 4]);
      racc += wv[0] * fmaf(cv[0], k1, k2) + wv[1] * fmaf(cv[1], k1, k2)
            + wv[2] * fmaf(cv[2], k1, k2) + wv[3] * fmaf(cv[3], k1, k2);
    }
    racc += __shfl_xor(racc, 1, 64); racc += __shfl_xor(racc, 2, 64);
    racc += __shfl_xor(racc, 4, 64);
    if (kl == 0){
      float bn = (racc - bn_rm[a]) * rsqrtf(bn_rv[a] + 1e-5f) * bn_g[a] + bn_b[a];
      red_s[a] = fmaxf(bn, 0.0f);
    }
  }
  __syncthreads();

  // sel -> 2-way softmax -> P,Q
  #pragma unroll
  for (int q = 0; q < 2; ++q){
    const int c = t + q * 256;
    const floatx4* ws0 = (const floatx4*)(w_sel + (size_t)c * 32);
    const floatx4* ws1 = (const floatx4*)(w_sel + (size_t)(CIN + c) * 32);
    float s0 = 0.f, s1 = 0.f;
    #pragma unroll
    for (int a4 = 0; a4 < 8; ++a4){
      floatx4 w0 = ws0[a4], w1 = ws1[a4];
      #pragma unroll
      for (int d = 0; d < 4; ++d){
        float r = red_s[a4 * 4 + d];
        s0 = fmaf(w0[d], r, s0);
        s1 = fmaf(w1[d], r, s1);
      }
    }
    float a0 = 1.f / (1.f + expf(s1 - s0));
    float a1 = 1.f - a0;
    float ch = ch_s[c];
    P[b*CIN + c] = 1.0f + a1 * ch;
    Q[b*CIN + c] = a0 * ch + a1;
  }

  // spatial softmax -> sp (unrolled 16-iter loops)
  const float* cb = ctxg + (size_t)b * HWN;
  float cm = -3.0e38f;
  #pragma unroll
  for (int i = 0; i < 16; ++i) cm = fmaxf(cm, cb[t + i * 256]);
  cm = bmax(cm, scr, t);
  float cs = 0.f;
  float ev[16];
  #pragma unroll
  for (int i = 0; i < 16; ++i){ ev[i] = expf(cb[t + i * 256] - cm); cs += ev[i]; }
  cs = bsum(cs, scr, t);
  const float inv = 1.0f / cs;
  #pragma unroll
  for (int i = 0; i < 16; ++i) sp[b*HWN + t + i * 256] = ev[i] * inv;
}

// ---------------- K5: out = x * (P + sp * Q), one block per (b,c) row ----------------
__global__ __launch_bounds__(256) void k5_out(
    const float* __restrict__ x, const float* __restrict__ P, const float* __restrict__ Q,
    const float* __restrict__ sp, float* __restrict__ out)
{
  const int bc = blockIdx.x;
  const int b = bc >> 9;
  const int t = threadIdx.x;
  const float p = P[bc], q = Q[bc];
  const floatx4* xr = (const floatx4*)(x + (size_t)bc * HWN);
  const floatx4* sr = (const floatx4*)(sp + (size_t)b * HWN);
  floatx4* outr = (floatx4*)(out + (size_t)bc * HWN);
  #pragma unroll
  for (int r = 0; r < 4; ++r){
    const int idx = t + r * 256;
    floatx4 xv = xr[idx];
    floatx4 sv = sr[idx];
    outr[idx] = xv * (p + sv * q);
  }
}

extern "C" void kernel_launch(void* const* d_in, const int* in_sizes, int n_in,
                              void* d_out, int out_size, void* d_ws, size_t ws_size,
                              hipStream_t stream)
{
  (void)in_sizes; (void)n_in; (void)out_size; (void)ws_size;
  const float* x    = (const float*)d_in[0];
  const float* w_qr = (const float*)d_in[1];
  const float* w_vr = (const float*)d_in[3];
  const float* b_vr = (const float*)d_in[4];
  const float* w_up = (const float*)d_in[5];
  const float* b_up = (const float*)d_in[6];
  const float* ln_g = (const float*)d_in[7];
  const float* ln_b = (const float*)d_in[8];
  const float* w_ql = (const float*)d_in[9];
  const float* b_ql = (const float*)d_in[10];
  const float* w_vl = (const float*)d_in[11];
  const float* w_red = (const float*)d_in[13];
  const float* bn_g  = (const float*)d_in[14];
  const float* bn_b  = (const float*)d_in[15];
  const float* bn_rm = (const float*)d_in[16];
  const float* bn_rv = (const float*)d_in[17];
  const float* w_sel = (const float*)d_in[18];
  float* out = (float*)d_out;

  char* ws = (char*)d_ws;
  unsigned short* wbf = (unsigned short*)(ws + 0);   //  262144 B
  float* qr    = (float*)(ws + 262144);              //  262144 B
  float* gpart = (float*)(ws + 524288);              // 1048576 B
  float* wmix  = (float*)(ws + 1572864);             //   32768 B
  float* xmask = (float*)(ws + 1605632);             //   32768 B (zeroed in KR2)
  float* ctx   = (float*)(ws + 1638400);             //  262144 B (zeroed in KR2)
  float* sp    = (float*)(ws + 1900544);             //  262144 B
  float* P     = (float*)(ws + 2162688);             //   32768 B
  float* Q     = (float*)(ws + 2195456);             //   32768 B
  float* stats = (float*)(ws + 2228224);             //     128 B
  float* gmax  = (float*)(ws + 2228352);             //   16384 B
  float* ctxm  = (float*)(ws + 2244736);             //   16384 B

  k0_convert<<<512, 256, 0, stream>>>(w_ql, wbf);
  k1_gemm<<<dim3(64, BATCH), 256, 0, stream>>>(x, wbf, w_qr, qr, gpart);
  kr1_gmax<<<dim3(BATCH, 8), 256, 0, stream>>>(gpart, b_ql, gmax);
  kr2_prep<<<dim3(BATCH, 5), 256, 0, stream>>>(gmax, w_vl, qr, wmix, stats, xmask, ctx);
  k3_dual<<<dim3(32, 4, BATCH), 256, 0, stream>>>(x, qr, stats, wmix, xmask, ctx);
  kr4_context<<<dim3(BATCH, 2), 256, 0, stream>>>(xmask, w_vr, b_vr, ctxm);
  kr5_tail<<<BATCH, 256, 0, stream>>>(ctxm, w_up, b_up, ln_g, ln_b,
                                      w_red, bn_g, bn_b, bn_rm, bn_rv, w_sel, ctx,
                                      P, Q, sp);
  k5_out<<<BATCH * CIN, 256, 0, stream>>>(x, P, Q, sp, out);
}

// Round 6
// 390.501 us; speedup vs baseline: 1.3778x; 1.0125x over previous
//
#include <hip/hip_runtime.h>
#include <hip/hip_bf16.h>

#define BATCH 16
#define CIN   512
#define CMID  256
#define HWN   4096

typedef __bf16 bf16x8  __attribute__((ext_vector_type(8)));
typedef float  floatx4 __attribute__((ext_vector_type(4)));
typedef int    intx4   __attribute__((ext_vector_type(4)));

__device__ __forceinline__ unsigned short f2bf(float f){
  union { float f; unsigned int u; } v; v.f = f;
  unsigned int u = v.u;
  unsigned int r = u + 0x7FFFu + ((u >> 16) & 1u);   // RTNE
  return (unsigned short)(r >> 16);
}

__device__ __forceinline__ float wred(float v){
  #pragma unroll
  for (int o = 32; o >= 1; o >>= 1) v += __shfl_xor(v, o, 64);
  return v;
}

__device__ __forceinline__ float bsum(float v, float* scr, int t){
  v = wred(v);
  __syncthreads();
  if ((t & 63) == 0) scr[t >> 6] = v;
  __syncthreads();
  return scr[0] + scr[1] + scr[2] + scr[3];
}

__device__ __forceinline__ float bmax(float v, float* scr, int t){
  #pragma unroll
  for (int o = 32; o >= 1; o >>= 1) v = fmaxf(v, __shfl_xor(v, o, 64));
  __syncthreads();
  if ((t & 63) == 0) scr[t >> 6] = v;
  __syncthreads();
  return fmaxf(fmaxf(scr[0], scr[1]), fmaxf(scr[2], scr[3]));
}

// ---------------- K0: w_ql fp32 -> bf16 ----------------
__global__ __launch_bounds__(256) void k0_convert(const float* __restrict__ w,
                                                  unsigned short* __restrict__ wbf){
  int i = blockIdx.x * 256 + threadIdx.x;
  wbf[i] = f2bf(w[i]);
}

// ---------------- K1: bf16 MFMA GEMM g_x = w_ql * x, keep row-max; fused fp32 qr ----
// Staging mapping (round 6): thread owns n = t&63, k-octet = wave, so every global
// load instr covers ONE k-row x 256 B contiguous (was 4x64-B segments -> 850 GB/s).
__global__ __launch_bounds__(256) void k1_gemm(
    const float* __restrict__ x, const unsigned short* __restrict__ wbf,
    const float* __restrict__ w_qr, float* __restrict__ qr, float* __restrict__ gpart)
{
  __shared__ __align__(16) unsigned short Blds[2][64 * 32];  // 2 x 4 KB, swizzled 16B blocks
  __shared__ float wqr_s[CIN];
  __shared__ float qp[4][64];

  const int t = threadIdx.x;
  const int ntile = blockIdx.x, b = blockIdx.y;
  const int n0 = ntile * 64;
  const int lane = t & 63, wave = t >> 6, quad = lane >> 4, lm = lane & 15;
  const int n_own = t & 63;     // row of B-tile this thread stages
  const int ko    = wave;       // k-octet (8 k) this thread stages
  // write target: 16B block phys = n*4 + (ko ^ (n&3)); bf16 index = phys*8
  const int wblk = (n_own * 4 + (ko ^ (n_own & 3))) * 8;

  wqr_s[t] = w_qr[t];
  wqr_s[t + 256] = w_qr[t + 256];
  __syncthreads();   // wqr_s read cross-wave below

  // base: row (ko*8), col n0 + n_own
  const float* xb = x + (size_t)b * CIN * HWN + (size_t)(ko * 8) * HWN + n0 + n_own;

  floatx4 acc[4][4];
  #pragma unroll
  for (int i = 0; i < 4; ++i)
    #pragma unroll
    for (int jj = 0; jj < 4; ++jj)
      acc[i][jj] = (floatx4){0.f, 0.f, 0.f, 0.f};

  float qa = 0.f;
  float xv[8];
  bf16x8 afc[4], afn[4];

  // ---- prologue: stage kt=0 into buf 0, prefetch A frags for kt=0 ----
  #pragma unroll
  for (int j = 0; j < 8; ++j) xv[j] = xb[(size_t)j * HWN];
  #pragma unroll
  for (int j = 0; j < 8; ++j) qa = fmaf(wqr_s[ko * 8 + j], xv[j], qa);
  {
    union { unsigned short u[8]; intx4 v; } pk;
    #pragma unroll
    for (int j = 0; j < 8; ++j) pk.u[j] = f2bf(xv[j]);
    *(intx4*)(&Blds[0][wblk]) = pk.v;
  }
  #pragma unroll
  for (int ms = 0; ms < 4; ++ms)
    afc[ms] = *(const bf16x8*)(&wbf[(size_t)(wave * 64 + ms * 16 + lm) * CIN + quad * 8]);
  __syncthreads();

  #pragma unroll 2
  for (int kt = 0; kt < 16; ++kt){
    const int cur = kt & 1;
    if (kt < 15){
      #pragma unroll
      for (int j = 0; j < 8; ++j) xv[j] = xb[(size_t)((kt + 1) * 32 + j) * HWN];
      #pragma unroll
      for (int ms = 0; ms < 4; ++ms)
        afn[ms] = *(const bf16x8*)(&wbf[(size_t)(wave * 64 + ms * 16 + lm) * CIN +
                                        (kt + 1) * 32 + quad * 8]);
    }
    bf16x8 bfr[4];
    #pragma unroll
    for (int ns = 0; ns < 4; ++ns){
      const int n = ns * 16 + lm;
      bfr[ns] = *(const bf16x8*)(&Blds[cur][(n * 4 + (quad ^ (n & 3))) * 8]);
    }
    #pragma unroll
    for (int ms = 0; ms < 4; ++ms)
      #pragma unroll
      for (int ns = 0; ns < 4; ++ns)
        acc[ms][ns] = __builtin_amdgcn_mfma_f32_16x16x32_bf16(afc[ms], bfr[ns], acc[ms][ns], 0, 0, 0);
    if (kt < 15){
      #pragma unroll
      for (int j = 0; j < 8; ++j)
        qa = fmaf(wqr_s[(kt + 1) * 32 + ko * 8 + j], xv[j], qa);
      union { unsigned short u[8]; intx4 v; } pk;
      #pragma unroll
      for (int j = 0; j < 8; ++j) pk.u[j] = f2bf(xv[j]);
      *(intx4*)(&Blds[1 - cur][wblk]) = pk.v;
      #pragma unroll
      for (int ms = 0; ms < 4; ++ms) afc[ms] = afn[ms];
    }
    __syncthreads();
  }

  // qr: each wave holds a k-octet partial for n = lane; reduce across waves via LDS
  qp[wave][lane] = qa;
  __syncthreads();
  if (t < 64) qr[b * HWN + n0 + t] = qp[0][t] + qp[1][t] + qp[2][t] + qp[3][t];

  // per-m max over this tile's 64 pixels
  #pragma unroll
  for (int ms = 0; ms < 4; ++ms){
    #pragma unroll
    for (int r = 0; r < 4; ++r){
      float v = fmaxf(fmaxf(acc[ms][0][r], acc[ms][1][r]),
                      fmaxf(acc[ms][2][r], acc[ms][3][r]));
      v = fmaxf(v, __shfl_xor(v, 1, 64));
      v = fmaxf(v, __shfl_xor(v, 2, 64));
      v = fmaxf(v, __shfl_xor(v, 4, 64));
      v = fmaxf(v, __shfl_xor(v, 8, 64));
      if ((lane & 15) == 0){
        const int m = wave * 64 + ms * 16 + (lane >> 4) * 4 + r;
        gpart[((b * 64 + ntile) * CMID) + m] = v;
      }
    }
  }
}

// ---------------- KR1: gmax[b,m] = max_nt gpart[b,nt,m] + b_ql[m] ; grid (16,8) ----
__global__ __launch_bounds__(256) void kr1_gmax(
    const float* __restrict__ gpart, const float* __restrict__ b_ql,
    float* __restrict__ gmax)
{
  __shared__ float part[8][32];
  const int b = blockIdx.x, g = blockIdx.y, t = threadIdx.x;
  const int m_l = t & 31, ng = t >> 5;
  const int m = g * 32 + m_l;
  float v = -3.0e38f;
  #pragma unroll
  for (int i = 0; i < 8; ++i)
    v = fmaxf(v, gpart[(size_t)(b * 64 + ng * 8 + i) * CMID + m]);
  part[ng][m_l] = v;
  __syncthreads();
  if (t < 32){
    float mx = part[0][t];
    #pragma unroll
    for (int i = 1; i < 8; ++i) mx = fmaxf(mx, part[i][t]);
    gmax[b * CMID + g * 32 + t] = mx + b_ql[g * 32 + t];
  }
}

// ---------------- KR2: grid (16,5). cg<4: softmax(gmax)->wmix slice + zero ctx quarter.
//                  cg==4: qr softmax stats + zero xmask. ----
__global__ __launch_bounds__(256) void kr2_prep(
    const float* __restrict__ gmax, const float* __restrict__ w_vl,
    const float* __restrict__ qr,
    float* __restrict__ wmix, float* __restrict__ stats,
    float* __restrict__ xmask, float* __restrict__ ctx)
{
  __shared__ float scr[4];
  __shared__ float avg_s[CMID];
  __shared__ float wsum[2][128];
  const int b = blockIdx.x, cg = blockIdx.y, t = threadIdx.x;

  if (cg < 4){
    ((floatx4*)(ctx + (size_t)b * HWN + cg * 1024))[t] = (floatx4){0.f,0.f,0.f,0.f};

    float gv = gmax[b * CMID + t];
    float mx = bmax(gv, scr, t);
    float e = expf(gv - mx);
    float s = bsum(e, scr, t);
    avg_s[t] = e / s;
    __syncthreads();

    const int c = cg * 128 + (t & 127);
    const int half = t >> 7;
    float acc = 0.f;
    #pragma unroll 8
    for (int mi = 0; mi < 128; ++mi){
      const int m = half * 128 + mi;
      acc = fmaf(w_vl[(size_t)m * CIN + c], avg_s[m], acc);
    }
    wsum[half][t & 127] = acc;
    __syncthreads();
    if (t < 128) wmix[b * CIN + cg * 128 + t] = wsum[0][t] + wsum[1][t];
  } else {
    xmask[b * CIN + t] = 0.f;
    xmask[b * CIN + t + 256] = 0.f;
    const float* qb = qr + (size_t)b * HWN;
    float qm = -3.0e38f;
    #pragma unroll
    for (int i = 0; i < 16; ++i) qm = fmaxf(qm, qb[t + i * 256]);
    qm = bmax(qm, scr, t);
    float qs = 0.f;
    #pragma unroll
    for (int i = 0; i < 16; ++i) qs += expf(qb[t + i * 256] - qm);
    qs = bsum(qs, scr, t);
    if (t == 0){ stats[b] = qm; stats[16 + b] = qs; }
  }
}

// ---------------- K3 (round 6): tile 64c x 256hw; each wave-instr reads one FULL
// 1-KB contiguous row slice (64 lanes x float4). grid (16 hwt, 8 ct, 16 b). ----
__global__ __launch_bounds__(256) void k3_dual(
    const float* __restrict__ x, const float* __restrict__ qr,
    const float* __restrict__ stats, const float* __restrict__ wmix,
    float* __restrict__ xmask, float* __restrict__ ctx)
{
  __shared__ floatx4 cxs[4][64];
  const int hwt = blockIdx.x, ct = blockIdx.y, b = blockIdx.z;
  const int t = threadIdx.x;
  const int lane = t & 63, wave = t >> 6;
  const int c0 = ct * 64 + wave * 16;       // this wave's 16 c-rows
  const int hw0 = hwt * 256;
  const float qm = stats[b], inv_qs = 1.0f / stats[16 + b];

  floatx4 maskv;
  {
    const float* qb = qr + (size_t)b * HWN + hw0 + lane * 4;
    #pragma unroll
    for (int d = 0; d < 4; ++d) maskv[d] = expf(qb[d] - qm) * inv_qs;
  }

  float wmv[16];
  #pragma unroll
  for (int r = 0; r < 16; ++r) wmv[r] = wmix[b*CIN + c0 + r];

  const float* xr0 = x + (size_t)b * CIN * HWN + (size_t)c0 * HWN + hw0 + lane * 4;

  floatx4 xv[16];
  #pragma unroll
  for (int r = 0; r < 16; ++r) xv[r] = *(const floatx4*)(xr0 + (size_t)r * HWN);

  // ctx partial: lane-local f4 over its 4 hw columns
  floatx4 cx = (floatx4){0.f,0.f,0.f,0.f};
  #pragma unroll
  for (int r = 0; r < 16; ++r) cx += xv[r] * wmv[r];

  // xmask: per-row dot with mask, wave-reduce, one atomic per row
  #pragma unroll
  for (int r = 0; r < 16; ++r){
    floatx4 p = xv[r] * maskv;
    float v = wred((p[0] + p[1]) + (p[2] + p[3]));
    if (lane == 0) atomicAdd(&xmask[b*CIN + c0 + r], v);
  }

  // ctx: cross-wave reduce in LDS, then 4 atomics per lane of wave 0
  cxs[wave][lane] = cx;
  __syncthreads();
  if (t < 64){
    floatx4 s = cxs[0][t] + cxs[1][t] + cxs[2][t] + cxs[3][t];
    #pragma unroll
    for (int d = 0; d < 4; ++d)
      atomicAdd(&ctx[b*HWN + hw0 + t*4 + d], s[d]);
  }
}

// ---------------- KR4: context[b,m] = w_vr[m,:].xmask[b] + b_vr[m] ; grid (16,2) ----
__global__ __launch_bounds__(256) void kr4_context(
    const float* __restrict__ xmask, const float* __restrict__ w_vr,
    const float* __restrict__ b_vr, float* __restrict__ ctxm)
{
  __shared__ __align__(16) float xm_s[CIN];
  const int b = blockIdx.x, half = blockIdx.y, t = threadIdx.x;
  const int kl = t & 15, rg = t >> 4;

  xm_s[t] = xmask[b * CIN + t];
  xm_s[t + 256] = xmask[b * CIN + t + 256];
  __syncthreads();

  floatx4 xf[8];
  #pragma unroll
  for (int jf = 0; jf < 8; ++jf)
    xf[jf] = *(const floatx4*)(&xm_s[(jf * 16 + kl) * 4]);

  #pragma unroll
  for (int pass = 0; pass < 8; ++pass){
    const int m = half * 128 + pass * 16 + rg;
    const floatx4* wr = (const floatx4*)(w_vr + (size_t)m * CIN);
    floatx4 pacc = (floatx4){0.f,0.f,0.f,0.f};
    #pragma unroll
    for (int jf = 0; jf < 8; ++jf)
      pacc += wr[jf * 16 + kl] * xf[jf];
    float acc = (pacc[0] + pacc[1]) + (pacc[2] + pacc[3]);
    acc += __shfl_xor(acc, 1, 64); acc += __shfl_xor(acc, 2, 64);
    acc += __shfl_xor(acc, 4, 64); acc += __shfl_xor(acc, 8, 64);
    if (kl == 0) ctxm[b * CMID + m] = acc + b_vr[m];
  }
}

// ---------------- KR5: up + LN + ch + red + sel -> P,Q ; spatial softmax -> sp ; grid 16 ----
__global__ __launch_bounds__(256) void kr5_tail(
    const float* __restrict__ ctxm, const float* __restrict__ w_up, const float* __restrict__ b_up,
    const float* __restrict__ ln_g, const float* __restrict__ ln_b,
    const float* __restrict__ w_red, const float* __restrict__ bn_g, const float* __restrict__ bn_b,
    const float* __restrict__ bn_rm, const float* __restrict__ bn_rv,
    const float* __restrict__ w_sel, const float* __restrict__ ctxg,
    float* __restrict__ P, float* __restrict__ Q, float* __restrict__ sp)
{
  __shared__ float scr[4];
  __shared__ __align__(16) float cm_s[CMID];
  __shared__ __align__(16) float up_s[CIN];
  __shared__ __align__(16) float ch_s[CIN];
  __shared__ float red_s[32];
  const int b = blockIdx.x, t = threadIdx.x;

  cm_s[t] = ctxm[b * CMID + t];
  __syncthreads();

  {
    const int kl = t & 7;
    floatx4 cf[8];
    #pragma unroll
    for (int jf = 0; jf < 8; ++jf)
      cf[jf] = *(const floatx4*)(&cm_s[(jf * 8 + kl) * 4]);
    #pragma unroll
    for (int pass = 0; pass < 16; ++pass){
      const int o = pass * 32 + (t >> 3);
      const floatx4* wr = (const floatx4*)(w_up + (size_t)o * CMID);
      floatx4 pacc = (floatx4){0.f,0.f,0.f,0.f};
      #pragma unroll
      for (int jf = 0; jf < 8; ++jf)
        pacc += wr[jf * 8 + kl] * cf[jf];
      float acc = (pacc[0] + pacc[1]) + (pacc[2] + pacc[3]);
      acc += __shfl_xor(acc, 1, 64); acc += __shfl_xor(acc, 2, 64);
      acc += __shfl_xor(acc, 4, 64);
      if (kl == 0) up_s[o] = acc + b_up[o];
    }
  }
  __syncthreads();

  float up0 = up_s[t], up1 = up_s[t + 256];
  float mu = bsum(up0 + up1, scr, t) * (1.0f / 512.0f);
  float d0 = up0 - mu, d1 = up1 - mu;
  float var = bsum(d0*d0 + d1*d1, scr, t) * (1.0f / 512.0f);
  float rstd = rsqrtf(var + 1e-5f);
  float ch0 = 1.f / (1.f + expf(-(d0 * rstd * ln_g[t] + ln_b[t])));
  float ch1 = 1.f / (1.f + expf(-(d1 * rstd * ln_g[t + 256] + ln_b[t + 256])));
  ch_s[t] = ch0; ch_s[t + 256] = ch1;
  __syncthreads();

  {
    const int kl = t & 7, a = t >> 3;
    const float k1 = 1.0f + 1.0f/4096.0f, k2 = 1.0f/4096.0f;
    const floatx4* wrd = (const floatx4*)(w_red + (size_t)a * CIN);
    float racc = 0.f;
    #pragma unroll
    for (int jf = 0; jf < 16; ++jf){
      floatx4 wv = wrd[jf * 8 + kl];
      floatx4 cv = *(const floatx4*)(&ch_s[(jf * 8 + kl) * 4]);
      racc += wv[0] * fmaf(cv[0], k1, k2) + wv[1] * fmaf(cv[1], k1, k2)
            + wv[2] * fmaf(cv[2], k1, k2) + wv[3] * fmaf(cv[3], k1, k2);
    }
    racc += __shfl_xor(racc, 1, 64); racc += __shfl_xor(racc, 2, 64);
    racc += __shfl_xor(racc, 4, 64);
    if (kl == 0){
      float bn = (racc - bn_rm[a]) * rsqrtf(bn_rv[a] + 1e-5f) * bn_g[a] + bn_b[a];
      red_s[a] = fmaxf(bn, 0.0f);
    }
  }
  __syncthreads();

  #pragma unroll
  for (int q = 0; q < 2; ++q){
    const int c = t + q * 256;
    const floatx4* ws0 = (const floatx4*)(w_sel + (size_t)c * 32);
    const floatx4* ws1 = (const floatx4*)(w_sel + (size_t)(CIN + c) * 32);
    float s0 = 0.f, s1 = 0.f;
    #pragma unroll
    for (int a4 = 0; a4 < 8; ++a4){
      floatx4 w0 = ws0[a4], w1 = ws1[a4];
      #pragma unroll
      for (int d = 0; d < 4; ++d){
        float r = red_s[a4 * 4 + d];
        s0 = fmaf(w0[d], r, s0);
        s1 = fmaf(w1[d], r, s1);
      }
    }
    float a0 = 1.f / (1.f + expf(s1 - s0));
    float a1 = 1.f - a0;
    float ch = ch_s[c];
    P[b*CIN + c] = 1.0f + a1 * ch;
    Q[b*CIN + c] = a0 * ch + a1;
  }

  const float* cb = ctxg + (size_t)b * HWN;
  float cm = -3.0e38f;
  #pragma unroll
  for (int i = 0; i < 16; ++i) cm = fmaxf(cm, cb[t + i * 256]);
  cm = bmax(cm, scr, t);
  float cs = 0.f;
  float ev[16];
  #pragma unroll
  for (int i = 0; i < 16; ++i){ ev[i] = expf(cb[t + i * 256] - cm); cs += ev[i]; }
  cs = bsum(cs, scr, t);
  const float inv = 1.0f / cs;
  #pragma unroll
  for (int i = 0; i < 16; ++i) sp[b*HWN + t + i * 256] = ev[i] * inv;
}

// ---------------- K5: out = x * (P + sp * Q), one block per (b,c) row ----------------
__global__ __launch_bounds__(256) void k5_out(
    const float* __restrict__ x, const float* __restrict__ P, const float* __restrict__ Q,
    const float* __restrict__ sp, float* __restrict__ out)
{
  const int bc = blockIdx.x;
  const int b = bc >> 9;
  const int t = threadIdx.x;
  const float p = P[bc], q = Q[bc];
  const floatx4* xr = (const floatx4*)(x + (size_t)bc * HWN);
  const floatx4* sr = (const floatx4*)(sp + (size_t)b * HWN);
  floatx4* outr = (floatx4*)(out + (size_t)bc * HWN);
  #pragma unroll
  for (int r = 0; r < 4; ++r){
    const int idx = t + r * 256;
    floatx4 xv = xr[idx];
    floatx4 sv = sr[idx];
    outr[idx] = xv * (p + sv * q);
  }
}

extern "C" void kernel_launch(void* const* d_in, const int* in_sizes, int n_in,
                              void* d_out, int out_size, void* d_ws, size_t ws_size,
                              hipStream_t stream)
{
  (void)in_sizes; (void)n_in; (void)out_size; (void)ws_size;
  const float* x    = (const float*)d_in[0];
  const float* w_qr = (const float*)d_in[1];
  const float* w_vr = (const float*)d_in[3];
  const float* b_vr = (const float*)d_in[4];
  const float* w_up = (const float*)d_in[5];
  const float* b_up = (const float*)d_in[6];
  const float* ln_g = (const float*)d_in[7];
  const float* ln_b = (const float*)d_in[8];
  const float* w_ql = (const float*)d_in[9];
  const float* b_ql = (const float*)d_in[10];
  const float* w_vl = (const float*)d_in[11];
  const float* w_red = (const float*)d_in[13];
  const float* bn_g  = (const float*)d_in[14];
  const float* bn_b  = (const float*)d_in[15];
  const float* bn_rm = (const float*)d_in[16];
  const float* bn_rv = (const float*)d_in[17];
  const float* w_sel = (const float*)d_in[18];
  float* out = (float*)d_out;

  char* ws = (char*)d_ws;
  unsigned short* wbf = (unsigned short*)(ws + 0);   //  262144 B
  float* qr    = (float*)(ws + 262144);              //  262144 B
  float* gpart = (float*)(ws + 524288);              // 1048576 B
  float* wmix  = (float*)(ws + 1572864);             //   32768 B
  float* xmask = (float*)(ws + 1605632);             //   32768 B (zeroed in KR2)
  float* ctx   = (float*)(ws + 1638400);             //  262144 B (zeroed in KR2)
  float* sp    = (float*)(ws + 1900544);             //  262144 B
  float* P     = (float*)(ws + 2162688);             //   32768 B
  float* Q     = (float*)(ws + 2195456);             //   32768 B
  float* stats = (float*)(ws + 2228224);             //     128 B
  float* gmax  = (float*)(ws + 2228352);             //   16384 B
  float* ctxm  = (float*)(ws + 2244736);             //   16384 B

  k0_convert<<<512, 256, 0, stream>>>(w_ql, wbf);
  k1_gemm<<<dim3(64, BATCH), 256, 0, stream>>>(x, wbf, w_qr, qr, gpart);
  kr1_gmax<<<dim3(BATCH, 8), 256, 0, stream>>>(gpart, b_ql, gmax);
  kr2_prep<<<dim3(BATCH, 5), 256, 0, stream>>>(gmax, w_vl, qr, wmix, stats, xmask, ctx);
  k3_dual<<<dim3(16, 8, BATCH), 256, 0, stream>>>(x, qr, stats, wmix, xmask, ctx);
  kr4_context<<<dim3(BATCH, 2), 256, 0, stream>>>(xmask, w_vr, b_vr, ctxm);
  kr5_tail<<<BATCH, 256, 0, stream>>>(ctxm, w_up, b_up, ln_g, ln_b,
                                      w_red, bn_g, bn_b, bn_rm, bn_rv, w_sel, ctx,
                                      P, Q, sp);
  k5_out<<<BATCH * CIN, 256, 0, stream>>>(x, P, Q, sp, out);
}